// Round 2
// baseline (198.496 us; speedup 1.0000x reference)
//
#include <hip/hip_runtime.h>

namespace {

constexpr int Bb   = 4;
constexpr int Nn   = 2048;
constexpr int Hh   = 16;
constexpr int Dd   = 32;
constexpr int C3   = 1536;   // 3*H*D
constexpr int Cc   = 512;    // H*D
constexpr int QBLK = 128;    // q rows per workgroup (32 per wave)
constexpr int KBLK = 32;     // kv rows per tile
constexpr int NIT  = Nn / KBLK;

using f16 = _Float16;
typedef f16   f16x4 __attribute__((ext_vector_type(4)));
typedef f16   f16x8 __attribute__((ext_vector_type(8)));
typedef float f32x4 __attribute__((ext_vector_type(4)));

__device__ __forceinline__ float fexp2(float x) { return exp2f(x); }

// legacy spelling (no underscore): A,B = f16x4 (2 VGPRs), C/D = f32x4
#define MFMA_PV(a, b, c) __builtin_amdgcn_mfma_f32_16x16x16f16((a), (b), (c), 0, 0, 0)

constexpr int KSTRIDE = 80;  // LDS row stride in bytes (64B data + 16B pad, 16B aligned)

__global__ __launch_bounds__(256, 4) void attn_fwd(const float* __restrict__ x,
                                                   float* __restrict__ out) {
  // K tile: rows = key 0..31 (d-major, fp16). V^T tile: rows = d 0..31 (key-major).
  __shared__ unsigned char lds[2 * KBLK * KSTRIDE];
  unsigned char* ldsK = lds;
  unsigned char* ldsV = lds + KBLK * KSTRIDE;

  const int tid  = threadIdx.x;
  const int lane = tid & 63;
  const int wv   = tid >> 6;     // wave 0..3
  const int m    = lane & 15;    // query-row / frag row within 16
  const int g    = lane >> 4;    // lane group 0..3

  const int bx = blockIdx.x;
  const int bh = bx & 63;        // bh-minor: keeps each (b,h)'s K/V on one XCD's L2
  const int qb = bx >> 6;        // 0..15
  const int b  = bh >> 4;
  const int h  = bh & 15;

  const float* xb = x + (size_t)b * Nn * C3;
  const float* qp = xb + h * Dd;
  const float* kp = xb + Cc + h * Dd;
  const float* vp = xb + 2 * Cc + h * Dd;

  // ---- Q fragments (2 m-tiles of 16 rows), pre-scaled by SCALE*log2(e) ----
  const float qscale = 0.17677669529663687f * 1.4426950408889634f;
  f16x8 qf[2];
#pragma unroll
  for (int mt = 0; mt < 2; ++mt) {
    int row = qb * QBLK + wv * 32 + mt * 16 + m;
    const float* qr = qp + (size_t)row * C3 + g * 8;
    float4 a = *(const float4*)qr;
    float4 c = *(const float4*)(qr + 4);
    qf[mt][0] = (f16)(a.x * qscale);
    qf[mt][1] = (f16)(a.y * qscale);
    qf[mt][2] = (f16)(a.z * qscale);
    qf[mt][3] = (f16)(a.w * qscale);
    qf[mt][4] = (f16)(c.x * qscale);
    qf[mt][5] = (f16)(c.y * qscale);
    qf[mt][6] = (f16)(c.z * qscale);
    qf[mt][7] = (f16)(c.w * qscale);
  }

  // ---- staging mapping: thread -> (key, 4 dims) ----
  const int skey = tid >> 3;          // 0..31
  const int sd4  = (tid & 7) * 4;     // 0,4,...,28
  const float* kg = kp + (size_t)skey * C3 + sd4;
  const float* vg = vp + (size_t)skey * C3 + sd4;
  unsigned char* kws = ldsK + skey * KSTRIDE + sd4 * 2;
  unsigned char* vws = ldsV + sd4 * KSTRIDE + skey * 2;

  // ---- accumulators / softmax state (per lane: row m of each m-tile) ----
  f32x4 acc[2][2] = {};               // [mt][dt] ; O^T[d=dt*16+4g+r][m]
  float mrun[2] = {-1e30f, -1e30f};
  float lrun[2] = {0.f, 0.f};

  // prologue: stage tile 0
  {
    float4 kf = *(const float4*)kg;
    float4 vf = *(const float4*)vg;
    *(f16x4*)kws = (f16x4){(f16)kf.x, (f16)kf.y, (f16)kf.z, (f16)kf.w};
    *(f16*)(vws + 0 * KSTRIDE) = (f16)vf.x;
    *(f16*)(vws + 1 * KSTRIDE) = (f16)vf.y;
    *(f16*)(vws + 2 * KSTRIDE) = (f16)vf.z;
    *(f16*)(vws + 3 * KSTRIDE) = (f16)vf.w;
  }
  __syncthreads();

  const unsigned char* kra0 = ldsK + m * KSTRIDE + g * 16;   // keys 0..15
  const unsigned char* kra1 = kra0 + 16 * KSTRIDE;           // keys 16..31
  const unsigned char* vra  = ldsV + m * KSTRIDE + g * 8;    // V^T rows

  const f32x4 z = {0.f, 0.f, 0.f, 0.f};

#pragma unroll 1
  for (int it = 0; it < NIT; ++it) {
    // prefetch next tile into registers (clamped on the last iter; always uniform)
    int nx = (it + 1 < NIT) ? it + 1 : NIT - 1;
    float4 kf = *(const float4*)(kg + (size_t)nx * KBLK * C3);
    float4 vf = *(const float4*)(vg + (size_t)nx * KBLK * C3);

    // K fragments (A-operand, shared by both m-tiles)
    f16x8 ka0 = *(const f16x8*)kra0;
    f16x8 ka1 = *(const f16x8*)kra1;

    // V^T fragments (A-operand of PV): [dt][chunk]
    f16x4 va[2][2];
#pragma unroll
    for (int dt = 0; dt < 2; ++dt)
#pragma unroll
      for (int c = 0; c < 2; ++c)
        va[dt][c] = *(const f16x4*)(vra + dt * 16 * KSTRIDE + c * 32);

#pragma unroll
    for (int mt = 0; mt < 2; ++mt) {
      // S^T tiles: lane holds S[m=l&15][n = nt*16 + 4g + r], log2-scaled
      f32x4 s0 = __builtin_amdgcn_mfma_f32_16x16x32_f16(ka0, qf[mt], z, 0, 0, 0);
      f32x4 s1 = __builtin_amdgcn_mfma_f32_16x16x32_f16(ka1, qf[mt], z, 0, 0, 0);

      // row max across this tile (in-lane 8 + cross-g reduce)
      float tmax = fmaxf(fmaxf(fmaxf(s0[0], s0[1]), fmaxf(s0[2], s0[3])),
                         fmaxf(fmaxf(s1[0], s1[1]), fmaxf(s1[2], s1[3])));
      tmax = fmaxf(tmax, __shfl_xor(tmax, 16));
      tmax = fmaxf(tmax, __shfl_xor(tmax, 32));

      if (__any(tmax > mrun[mt])) {      // exact, wave-uniform rescale skip
        float mnew  = fmaxf(mrun[mt], tmax);
        float alpha = fexp2(mrun[mt] - mnew);
        lrun[mt] *= alpha;
#pragma unroll
        for (int dt = 0; dt < 2; ++dt) {
          acc[mt][dt][0] *= alpha; acc[mt][dt][1] *= alpha;
          acc[mt][dt][2] *= alpha; acc[mt][dt][3] *= alpha;
        }
        mrun[mt] = mnew;
      }

      f32x4 p0, p1;
#pragma unroll
      for (int r = 0; r < 4; ++r) p0[r] = fexp2(s0[r] - mrun[mt]);
#pragma unroll
      for (int r = 0; r < 4; ++r) p1[r] = fexp2(s1[r] - mrun[mt]);

      float tsum = (p0[0] + p0[1]) + (p0[2] + p0[3]) +
                   (p1[0] + p1[1]) + (p1[2] + p1[3]);
      tsum += __shfl_xor(tsum, 16);
      tsum += __shfl_xor(tsum, 32);
      lrun[mt] += tsum;

      // P -> fp16 B-fragments (layout matches mfma_16x16x16 B directly)
      f16x4 pb0 = {(f16)p0[0], (f16)p0[1], (f16)p0[2], (f16)p0[3]};
      f16x4 pb1 = {(f16)p1[0], (f16)p1[1], (f16)p1[2], (f16)p1[3]};

#pragma unroll
      for (int dt = 0; dt < 2; ++dt) {
        acc[mt][dt] = MFMA_PV(va[dt][0], pb0, acc[mt][dt]);
        acc[mt][dt] = MFMA_PV(va[dt][1], pb1, acc[mt][dt]);
      }
    }

    __syncthreads();
    // write next tile (redundant rewrite of last tile on final iter — harmless)
    *(f16x4*)kws = (f16x4){(f16)kf.x, (f16)kf.y, (f16)kf.z, (f16)kf.w};
    *(f16*)(vws + 0 * KSTRIDE) = (f16)vf.x;
    *(f16*)(vws + 1 * KSTRIDE) = (f16)vf.y;
    *(f16*)(vws + 2 * KSTRIDE) = (f16)vf.z;
    *(f16*)(vws + 3 * KSTRIDE) = (f16)vf.w;
    __syncthreads();
  }

  // ---- epilogue: normalize and store O^T -> out[b][n][h*32+d] ----
#pragma unroll
  for (int mt = 0; mt < 2; ++mt) {
    float inv = 1.0f / lrun[mt];
    int row = qb * QBLK + wv * 32 + mt * 16 + m;
    float* op = out + ((size_t)b * Nn + row) * Cc + h * Dd;
#pragma unroll
    for (int dt = 0; dt < 2; ++dt) {
      f32x4 o;
      o[0] = acc[mt][dt][0] * inv;
      o[1] = acc[mt][dt][1] * inv;
      o[2] = acc[mt][dt][2] * inv;
      o[3] = acc[mt][dt][3] * inv;
      *(f32x4*)(op + dt * 16 + g * 4) = o;
    }
  }
}

}  // namespace

extern "C" void kernel_launch(void* const* d_in, const int* in_sizes, int n_in,
                              void* d_out, int out_size, void* d_ws, size_t ws_size,
                              hipStream_t stream) {
  const float* x = (const float*)d_in[0];
  float* outp    = (float*)d_out;
  attn_fwd<<<dim3(Bb * Hh * (Nn / QBLK)), dim3(256), 0, stream>>>(x, outp);
}

// Round 5
// 152.117 us; speedup vs baseline: 1.3049x; 1.3049x over previous
//
#include <hip/hip_runtime.h>

namespace {

constexpr int Bb   = 4;
constexpr int Nn   = 2048;
constexpr int Hh   = 16;
constexpr int Dd   = 32;
constexpr int C3   = 1536;   // 3*H*D
constexpr int Cc   = 512;    // H*D
constexpr int QBLK = 64;     // q rows per workgroup (16 per wave)
constexpr int KBLK = 32;     // kv rows per tile
constexpr int NIT  = Nn / KBLK;
constexpr float THR = 8.0f;  // defer-max threshold (log2 domain); P <= 2^8, f16-safe

using f16 = _Float16;
typedef f16   f16x2 __attribute__((ext_vector_type(2)));
typedef f16   f16x4 __attribute__((ext_vector_type(4)));
typedef f16   f16x8 __attribute__((ext_vector_type(8)));
typedef float f32x4 __attribute__((ext_vector_type(4)));

#if __has_builtin(__builtin_amdgcn_exp2f)
__device__ __forceinline__ float fexp2(float x) { return __builtin_amdgcn_exp2f(x); }
#else
__device__ __forceinline__ float fexp2(float x) { return exp2f(x); }
#endif

__device__ __forceinline__ f16x4 pk4(float a, float b, float c, float d) {
  f16x2 lo = __builtin_bit_cast(f16x2, __builtin_amdgcn_cvt_pkrtz(a, b));
  f16x2 hi = __builtin_bit_cast(f16x2, __builtin_amdgcn_cvt_pkrtz(c, d));
  f16x4 r;
  r[0] = lo[0]; r[1] = lo[1]; r[2] = hi[0]; r[3] = hi[1];
  return r;
}

#define MFMA16(a, b, c) __builtin_amdgcn_mfma_f32_16x16x16f16((a), (b), (c), 0, 0, 0)
#define MFMA32(a, b, c) __builtin_amdgcn_mfma_f32_16x16x32_f16((a), (b), (c), 0, 0, 0)

constexpr int KST = 80;  // K row stride bytes (64B data + 16B pad)
constexpr int VST = 72;  // V^T row stride bytes (64B data + 8B pad)

__global__ __launch_bounds__(256, 8) void attn_fwd(const float* __restrict__ x,
                                                   float* __restrict__ out) {
  __shared__ unsigned char ldsK[2][KBLK * KST];  // [buf][key][d] f16
  __shared__ unsigned char ldsV[2][Dd * VST];    // [buf][d][key] f16 (V^T)

  const int tid  = threadIdx.x;
  const int lane = tid & 63;
  const int wv   = tid >> 6;     // wave 0..3
  const int m    = lane & 15;    // query col within 16 (C/D col = lane&15)
  const int g    = lane >> 4;    // lane group 0..3

  const int bx = blockIdx.x;
  const int bh = bx & 63;        // bh-minor: same (b,h) blocks land on same XCD
  const int qb = bx >> 6;        // 0..31
  const int b  = bh >> 4;
  const int h  = bh & 15;

  const float* xb = x + (size_t)b * Nn * C3;
  const float* kp = xb + Cc + h * Dd;
  const float* vp = xb + 2 * Cc + h * Dd;

  // ---- Q fragment (B-operand of QK^T), pre-scaled by SCALE*log2(e) ----
  const float qs = 0.17677669529663687f * 1.4426950408889634f;
  const int qrow = qb * QBLK + wv * 16 + m;
  const float* qr = xb + (size_t)qrow * C3 + h * Dd + g * 8;
  float4 qa = *(const float4*)qr;
  float4 qc = *(const float4*)(qr + 4);
  f16x8 qf;
  {
    f16x4 lo = pk4(qa.x * qs, qa.y * qs, qa.z * qs, qa.w * qs);
    f16x4 hi = pk4(qc.x * qs, qc.y * qs, qc.z * qs, qc.w * qs);
    qf[0] = lo[0]; qf[1] = lo[1]; qf[2] = lo[2]; qf[3] = lo[3];
    qf[4] = hi[0]; qf[5] = hi[1]; qf[6] = hi[2]; qf[7] = hi[3];
  }

  // ---- staging map: thread -> (key, 4 dims) ----
  const int skey = tid >> 3;          // 0..31
  const int sd4  = (tid & 7) * 4;     // 0,4,...,28
  const float* kgp = kp + (size_t)skey * C3 + sd4;
  const float* vgp = vp + (size_t)skey * C3 + sd4;

  const f16x4 ones = {(f16)1.f, (f16)1.f, (f16)1.f, (f16)1.f};

  f32x4 acc0 = {};   // O^T[d=4g+r][q=m]      (dt=0)
  f32x4 acc1 = {};   // O^T[d=16+4g+r][q=m]   (dt=1)
  f32x4 lsum = {};   // sum_k P[k][q=m], replicated across regs
  float mrun = 0.f;

  // prologue: stage tile 0 into buf 0
  {
    float4 kf = *(const float4*)kgp;
    float4 vf = *(const float4*)vgp;
    *(f16x4*)(ldsK[0] + skey * KST + sd4 * 2) = pk4(kf.x, kf.y, kf.z, kf.w);
    unsigned char* vw = ldsV[0] + sd4 * VST + skey * 2;
    *(f16*)(vw + 0 * VST) = (f16)vf.x;
    *(f16*)(vw + 1 * VST) = (f16)vf.y;
    *(f16*)(vw + 2 * VST) = (f16)vf.z;
    *(f16*)(vw + 3 * VST) = (f16)vf.w;
  }
  __syncthreads();

  int cur = 0;
#pragma unroll 2
  for (int it = 0; it < NIT; ++it) {
    // prefetch next tile (uniform branch; last iter re-reads current)
    if (it + 1 < NIT) { kgp += KBLK * C3; vgp += KBLK * C3; }
    float4 kf = *(const float4*)kgp;
    float4 vf = *(const float4*)vgp;

    const unsigned char* Kb = ldsK[cur];
    const unsigned char* Vb = ldsV[cur];

    // K fragments: A[row=key][k=d]; keys 0..15 and 16..31
    f16x8 ka0 = *(const f16x8*)(Kb + m * KST + g * 16);
    f16x8 ka1 = *(const f16x8*)(Kb + (16 + m) * KST + g * 16);
    // V^T fragments: A[row=d][k=key]; [dt][chunk]
    f16x4 va00 = *(const f16x4*)(Vb + m * VST + (4 * g) * 2);
    f16x4 va01 = *(const f16x4*)(Vb + m * VST + (16 + 4 * g) * 2);
    f16x4 va10 = *(const f16x4*)(Vb + (16 + m) * VST + (4 * g) * 2);
    f16x4 va11 = *(const f16x4*)(Vb + (16 + m) * VST + (16 + 4 * g) * 2);

    // QK^T with C = -mrun: s' = q.k - mrun directly (C const over rows = per-lane)
    f32x4 cvec = {-mrun, -mrun, -mrun, -mrun};
    f32x4 s0 = MFMA32(ka0, qf, cvec);
    f32x4 s1 = MFMA32(ka1, qf, cvec);

    // defer-max: local 8-value max, rescale only if any lane exceeds THR (rare)
    float tl = fmaxf(fmaxf(fmaxf(s0[0], s0[1]), fmaxf(s0[2], s0[3])),
                     fmaxf(fmaxf(s1[0], s1[1]), fmaxf(s1[2], s1[3])));
    if (__builtin_expect(__any(tl > THR), 0)) {
      float t = fmaxf(tl, __shfl_xor(tl, 16));
      t = fmaxf(t, __shfl_xor(t, 32));
      float d = fmaxf(t, 0.f);
      float al = fexp2(-d);
#pragma unroll
      for (int r = 0; r < 4; ++r) {
        acc0[r] *= al; acc1[r] *= al; lsum[r] *= al;
        s0[r] -= d; s1[r] -= d;
      }
      mrun += d;
    }

    f32x4 p0, p1;
#pragma unroll
    for (int r = 0; r < 4; ++r) p0[r] = fexp2(s0[r]);
#pragma unroll
    for (int r = 0; r < 4; ++r) p1[r] = fexp2(s1[r]);

    f16x4 pb0 = pk4(p0[0], p0[1], p0[2], p0[3]);  // keys 0..15 chunk
    f16x4 pb1 = pk4(p1[0], p1[1], p1[2], p1[3]);  // keys 16..31 chunk

    acc0 = MFMA16(va00, pb0, acc0);
    acc0 = MFMA16(va01, pb1, acc0);
    acc1 = MFMA16(va10, pb0, acc1);
    acc1 = MFMA16(va11, pb1, acc1);
    lsum = MFMA16(ones, pb0, lsum);   // row-sum of P via MFMA (all regs = total)
    lsum = MFMA16(ones, pb1, lsum);

    // stage next tile into alternate buffer; single barrier per iteration
    *(f16x4*)(ldsK[cur ^ 1] + skey * KST + sd4 * 2) = pk4(kf.x, kf.y, kf.z, kf.w);
    unsigned char* vw = ldsV[cur ^ 1] + sd4 * VST + skey * 2;
    *(f16*)(vw + 0 * VST) = (f16)vf.x;
    *(f16*)(vw + 1 * VST) = (f16)vf.y;
    *(f16*)(vw + 2 * VST) = (f16)vf.z;
    *(f16*)(vw + 3 * VST) = (f16)vf.w;
    __syncthreads();
    cur ^= 1;
  }

  // ---- epilogue: normalize, store O^T -> out[b][qrow][h*32 + d] ----
  float inv = 1.0f / lsum[0];
  float* op = out + ((size_t)b * Nn + qrow) * Cc + h * Dd;
  f32x4 o0, o1;
#pragma unroll
  for (int r = 0; r < 4; ++r) { o0[r] = acc0[r] * inv; o1[r] = acc1[r] * inv; }
  *(f32x4*)(op + g * 4)      = o0;
  *(f32x4*)(op + 16 + g * 4) = o1;
}

}  // namespace

extern "C" void kernel_launch(void* const* d_in, const int* in_sizes, int n_in,
                              void* d_out, int out_size, void* d_ws, size_t ws_size,
                              hipStream_t stream) {
  const float* x = (const float*)d_in[0];
  float* outp    = (float*)d_out;
  attn_fwd<<<dim3(Bb * Hh * (Nn / QBLK)), dim3(256), 0, stream>>>(x, outp);
}

// Round 6
// 138.528 us; speedup vs baseline: 1.4329x; 1.0981x over previous
//
#include <hip/hip_runtime.h>

namespace {

constexpr int Bb   = 4;
constexpr int Nn   = 2048;
constexpr int Hh   = 16;
constexpr int Dd   = 32;
constexpr int C3   = 1536;   // 3*H*D
constexpr int Cc   = 512;    // H*D
constexpr int QBLK = 128;    // q rows per workgroup (32 per wave, 2 m-tiles)
constexpr int KBLK = 32;     // kv rows per tile
constexpr int NIT  = Nn / KBLK;
constexpr float THR = 11.0f; // defer-max threshold (log2 domain); P <= 2^11, f16-safe

using f16 = _Float16;
typedef f16   f16x2 __attribute__((ext_vector_type(2)));
typedef f16   f16x4 __attribute__((ext_vector_type(4)));
typedef f16   f16x8 __attribute__((ext_vector_type(8)));
typedef float f32x4 __attribute__((ext_vector_type(4)));

#if __has_builtin(__builtin_amdgcn_exp2f)
__device__ __forceinline__ float fexp2(float x) { return __builtin_amdgcn_exp2f(x); }
#else
__device__ __forceinline__ float fexp2(float x) { return exp2f(x); }
#endif

__device__ __forceinline__ f16x4 pk4(float a, float b, float c, float d) {
  f16x2 lo = __builtin_bit_cast(f16x2, __builtin_amdgcn_cvt_pkrtz(a, b));
  f16x2 hi = __builtin_bit_cast(f16x2, __builtin_amdgcn_cvt_pkrtz(c, d));
  f16x4 r;
  r[0] = lo[0]; r[1] = lo[1]; r[2] = hi[0]; r[3] = hi[1];
  return r;
}

#define MFMA16(a, b, c) __builtin_amdgcn_mfma_f32_16x16x16f16((a), (b), (c), 0, 0, 0)
#define MFMA32(a, b, c) __builtin_amdgcn_mfma_f32_16x16x32_f16((a), (b), (c), 0, 0, 0)

constexpr int KST = 80;  // K row stride bytes: banks 20*skey+2*(t&7) -> 2-way max (free)
constexpr int VST = 72;  // V^T row stride bytes: reads 18m distinct banks; writes at
                         // rows sdv+8j -> banks 18*(sdv+8j)%32 all distinct (conflict-free)

__global__ __launch_bounds__(256, 4) void attn_fwd(const float* __restrict__ x,
                                                   float* __restrict__ out) {
  __shared__ unsigned char ldsK[2][KBLK * KST];  // [buf][key][d] f16
  __shared__ unsigned char ldsV[2][Dd * VST];    // [buf][d][key] f16 (V^T)

  const int tid  = threadIdx.x;
  const int lane = tid & 63;
  const int wv   = tid >> 6;     // wave 0..3
  const int m    = lane & 15;    // query col within 16 (C/D col = lane&15)
  const int g    = lane >> 4;    // lane group 0..3

  const int bx = blockIdx.x;
  const int bh = bx & 63;        // bh-minor: same-(b,h) q-blocks land on same XCD (64k===0 mod 8)
  const int qb = bx >> 6;        // 0..15
  const int b  = bh >> 4;
  const int h  = bh & 15;

  const float* xb = x + (size_t)b * Nn * C3;
  const float* xk = xb + Cc + h * Dd;       // K base (uniform)
  const float* xv = xb + 2 * Cc + h * Dd;   // V base (uniform)

  // ---- Q fragments (2 m-tiles), pre-scaled by SCALE*log2(e) ----
  const float qs = 0.17677669529663687f * 1.4426950408889634f;
  const int qrow0 = qb * QBLK + wv * 32;
  f16x8 qf[2];
#pragma unroll
  for (int mt = 0; mt < 2; ++mt) {
    const float* qr = xb + (size_t)(qrow0 + mt * 16 + m) * C3 + h * Dd + g * 8;
    float4 qa = *(const float4*)qr;
    float4 qc = *(const float4*)(qr + 4);
    f16x4 lo = pk4(qa.x * qs, qa.y * qs, qa.z * qs, qa.w * qs);
    f16x4 hi = pk4(qc.x * qs, qc.y * qs, qc.z * qs, qc.w * qs);
    qf[mt][0] = lo[0]; qf[mt][1] = lo[1]; qf[mt][2] = lo[2]; qf[mt][3] = lo[3];
    qf[mt][4] = hi[0]; qf[mt][5] = hi[1]; qf[mt][6] = hi[2]; qf[mt][7] = hi[3];
  }

  // ---- staging maps (thread-constant indices; loads use uniform-ptr + vindex) ----
  const int skey = tid >> 3;                 // 0..31
  const int sd4  = (tid & 7) * 4;            // K dims: 4 contiguous
  const int sdv  = tid & 7;                  // V dims: {sdv, sdv+8, sdv+16, sdv+24}
  const int kofs = skey * C3 + sd4;          // float index
  const int vofs = skey * C3 + sdv;

  const f16x4 ones = {(f16)1.f, (f16)1.f, (f16)1.f, (f16)1.f};

  f32x4 acc[2][2] = {};           // [mt][dt] ; O^T[d = dt*16 + 4g + r][q=m]
  f32x4 lsum[2] = {};             // per-mt sum_k P, replicated
  f32x4 negm[2] = {};             // per-mt {-mrun} x4 (MFMA C operand)

  // prologue: stage tile 0 into buf 0
  {
    float4 kf = *(const float4*)(xk + kofs);
    float v0 = xv[vofs], v1 = xv[vofs + 8], v2 = xv[vofs + 16], v3 = xv[vofs + 24];
    *(f16x4*)(ldsK[0] + skey * KST + sd4 * 2) = pk4(kf.x, kf.y, kf.z, kf.w);
    unsigned char* vw = ldsV[0] + sdv * VST + skey * 2;
    *(f16*)(vw + 0 * 8 * VST) = (f16)v0;
    *(f16*)(vw + 1 * 8 * VST) = (f16)v1;
    *(f16*)(vw + 2 * 8 * VST) = (f16)v2;
    *(f16*)(vw + 3 * 8 * VST) = (f16)v3;
  }
  __syncthreads();

  int cur = 0;
#pragma unroll 2
  for (int it = 0; it < NIT; ++it) {
    // prefetch next tile (uniform scalar offset -> saddr-form loads)
    const int nx = (it + 1 < NIT) ? it + 1 : it;
    const float* xk2 = xk + nx * KBLK * C3;
    const float* xv2 = xv + nx * KBLK * C3;
    float4 kf = *(const float4*)(xk2 + kofs);
    float v0 = xv2[vofs], v1 = xv2[vofs + 8], v2 = xv2[vofs + 16], v3 = xv2[vofs + 24];

    const unsigned char* Kb = ldsK[cur];
    const unsigned char* Vb = ldsV[cur];

    // K / V^T fragments — mt-independent, read once per tile
    f16x8 ka0 = *(const f16x8*)(Kb + m * KST + g * 16);
    f16x8 ka1 = *(const f16x8*)(Kb + (16 + m) * KST + g * 16);
    f16x4 va00 = *(const f16x4*)(Vb + m * VST + 8 * g);
    f16x4 va01 = *(const f16x4*)(Vb + m * VST + 32 + 8 * g);
    f16x4 va10 = *(const f16x4*)(Vb + (16 + m) * VST + 8 * g);
    f16x4 va11 = *(const f16x4*)(Vb + (16 + m) * VST + 32 + 8 * g);

#pragma unroll
    for (int mt = 0; mt < 2; ++mt) {
      // s' = q.k - mrun via MFMA C operand (negm persistent, updated only on rescale)
      f32x4 s0 = MFMA32(ka0, qf[mt], negm[mt]);
      f32x4 s1 = MFMA32(ka1, qf[mt], negm[mt]);

      // per-lane 8-value max (max3-fusable tree), rare wave-uniform rescale
      float a1 = fmaxf(fmaxf(s0[0], s0[1]), s0[2]);
      float a2 = fmaxf(fmaxf(s0[3], s1[0]), s1[1]);
      float a3 = fmaxf(fmaxf(s1[2], s1[3]), a1);
      float tl = fmaxf(a2, a3);
      if (__builtin_expect(__any(tl > THR), 0)) {
        float t = fmaxf(tl, __shfl_xor(tl, 16));
        t = fmaxf(t, __shfl_xor(t, 32));
        float d = fmaxf(t, 0.f);
        float al = fexp2(-d);
#pragma unroll
        for (int r = 0; r < 4; ++r) {
          acc[mt][0][r] *= al; acc[mt][1][r] *= al; lsum[mt][r] *= al;
          s0[r] -= d; s1[r] -= d;
          negm[mt][r] -= d;
        }
      }

      f32x4 p0, p1;
#pragma unroll
      for (int r = 0; r < 4; ++r) p0[r] = fexp2(s0[r]);
#pragma unroll
      for (int r = 0; r < 4; ++r) p1[r] = fexp2(s1[r]);

      f16x4 pb0 = pk4(p0[0], p0[1], p0[2], p0[3]);  // keys 0..15
      f16x4 pb1 = pk4(p1[0], p1[1], p1[2], p1[3]);  // keys 16..31

      acc[mt][0] = MFMA16(va00, pb0, acc[mt][0]);
      acc[mt][0] = MFMA16(va01, pb1, acc[mt][0]);
      acc[mt][1] = MFMA16(va10, pb0, acc[mt][1]);
      acc[mt][1] = MFMA16(va11, pb1, acc[mt][1]);
      lsum[mt] = MFMA16(ones, pb0, lsum[mt]);       // row-sum of quantized P
      lsum[mt] = MFMA16(ones, pb1, lsum[mt]);
    }

    // stage next tile into alternate buffer; single barrier per iteration
    *(f16x4*)(ldsK[cur ^ 1] + skey * KST + sd4 * 2) = pk4(kf.x, kf.y, kf.z, kf.w);
    unsigned char* vw = ldsV[cur ^ 1] + sdv * VST + skey * 2;
    *(f16*)(vw + 0 * 8 * VST) = (f16)v0;
    *(f16*)(vw + 1 * 8 * VST) = (f16)v1;
    *(f16*)(vw + 2 * 8 * VST) = (f16)v2;
    *(f16*)(vw + 3 * 8 * VST) = (f16)v3;
    __syncthreads();
    cur ^= 1;
  }

  // ---- epilogue: normalize, store O^T -> out[b][qrow][h*32 + d] ----
#pragma unroll
  for (int mt = 0; mt < 2; ++mt) {
    float inv = 1.0f / lsum[mt][0];
    float* op = out + ((size_t)b * Nn + (qrow0 + mt * 16 + m)) * Cc + h * Dd;
    f32x4 o0, o1;
#pragma unroll
    for (int r = 0; r < 4; ++r) { o0[r] = acc[mt][0][r] * inv; o1[r] = acc[mt][1][r] * inv; }
    *(f32x4*)(op + g * 4)      = o0;
    *(f32x4*)(op + 16 + g * 4) = o1;
  }
}

}  // namespace

extern "C" void kernel_launch(void* const* d_in, const int* in_sizes, int n_in,
                              void* d_out, int out_size, void* d_ws, size_t ws_size,
                              hipStream_t stream) {
  const float* x = (const float*)d_in[0];
  float* outp    = (float*)d_out;
  attn_fwd<<<dim3(Bb * Hh * (Nn / QBLK)), dim3(256), 0, stream>>>(x, outp);
}